// Round 1
// baseline (64.020 us; speedup 1.0000x reference)
//
#include <hip/hip_runtime.h>

// out[i] = sum_h relu(diag_i * W1[h] + b1[h]) * W2[h] + b2[0]
// where diag_i = exp(-gamma * (xn - 2*xn + xn)), xn = X[i]^2  (== 1.0 exactly,
// but computed faithfully per the reference formula).
__global__ __launch_bounds__(256) void qkrg_kernel(
    const float* __restrict__ X,
    const float* __restrict__ gamma,
    const float* __restrict__ W1,
    const float* __restrict__ b1,
    const float* __restrict__ W2,
    const float* __restrict__ b2,
    float* __restrict__ out,
    int N)
{
    int i = blockIdx.x * blockDim.x + threadIdx.x;
    if (i >= N) return;

    float x  = X[i];
    float xn = x * x;
    // Faithful to reference: x_norm - 2*(X@X.T)_ii + x_norm; for F=1 the
    // matmul diagonal element is exactly xn.
    float sq = xn - 2.0f * xn + xn;          // == 0.0f exactly in fp32
    float d  = expf(-gamma[0] * sq);         // == 1.0f

    float acc = b2[0];
#pragma unroll
    for (int h = 0; h < 32; ++h) {
        float v = fmaf(d, W1[h], b1[h]);     // diag @ W1 + b1
        v = v > 0.0f ? v : 0.0f;             // relu
        acc = fmaf(v, W2[h], acc);           // h @ W2 + b2
    }
    out[i] = acc;
}

extern "C" void kernel_launch(void* const* d_in, const int* in_sizes, int n_in,
                              void* d_out, int out_size, void* d_ws, size_t ws_size,
                              hipStream_t stream)
{
    const float* X     = (const float*)d_in[0];   // [N,1] fp32
    const float* gamma = (const float*)d_in[1];   // scalar
    const float* W1    = (const float*)d_in[2];   // [1,32]
    const float* b1    = (const float*)d_in[3];   // [32]
    const float* W2    = (const float*)d_in[4];   // [32,1]
    const float* b2    = (const float*)d_in[5];   // [1]
    float* out = (float*)d_out;

    int N = out_size;                             // 16384
    int block = 256;
    int grid  = (N + block - 1) / block;          // 64 blocks
    qkrg_kernel<<<grid, block, 0, stream>>>(X, gamma, W1, b1, W2, b2, out, N);
}